// Round 1
// baseline (594.877 us; speedup 1.0000x reference)
//
#include <hip/hip_runtime.h>
#include <math.h>

// Actor_att1: B=262144 rows, obs=127 fp32.
// Thread-per-row, all-register compute, weights via thread-uniform (scalar) loads.
// fp32 throughout (threshold is 2% of max|ref|; fp32 gives ~1e-5).

#define OBS 127
#define NG  16   // N_GOOD
#define NU  32   // NUM_UNITS
#define NT  16   // NUM_TEST

__device__ __forceinline__ float lrelu(float v) { return fmaxf(v, 0.01f * v); }

__global__ __launch_bounds__(256)
void actor_kernel(const float* __restrict__ x,
                  const float* __restrict__ en_w1, const float* __restrict__ en_b1,
                  const float* __restrict__ en_w2, const float* __restrict__ en_b2,
                  const float* __restrict__ oa_w1, const float* __restrict__ oa_b1,
                  const float* __restrict__ oa_w2, const float* __restrict__ oa_b2,
                  const float* __restrict__ oa_g,  const float* __restrict__ oa_bln,
                  const float* __restrict__ g_w1,  const float* __restrict__ g_b1,
                  const float* __restrict__ g_w2,  const float* __restrict__ g_b2,
                  const float* __restrict__ g_g,   const float* __restrict__ g_bln,
                  const float* __restrict__ m_w1,  const float* __restrict__ m_b1,
                  const float* __restrict__ m_w2,  const float* __restrict__ m_b2,
                  const float* __restrict__ m_w3,  const float* __restrict__ m_b3,
                  float* __restrict__ out, int B)
{
    const int row = blockIdx.x * blockDim.x + threadIdx.x;
    if (row >= B) return;
    const float* __restrict__ xr = x + (long)row * OBS;

    // ---- self encoder: 4 -> 32 relu -> 16 relu ----
    float self_o[NT];
    {
        const float x0 = xr[0], x1 = xr[1], x2 = xr[2], x3 = xr[3];
        float h[NU];
        #pragma unroll
        for (int j = 0; j < NU; ++j) {
            float a = en_b1[j];
            a += x0 * en_w1[0 * NU + j];
            a += x1 * en_w1[1 * NU + j];
            a += x2 * en_w1[2 * NU + j];
            a += x3 * en_w1[3 * NU + j];
            h[j] = fmaxf(a, 0.f);
        }
        #pragma unroll
        for (int j = 0; j < NT; ++j) {
            float a = en_b2[j];
            #pragma unroll
            for (int k = 0; k < NU; ++k) a += h[k] * en_w2[k * NT + j];
            self_o[j] = fmaxf(a, 0.f);
        }
    }

    // ---- other-agent branch: 15 entities, 5 -> 32 -> 16, attend, LN+relu ----
    float other_o[NT];
    {
        float m = -1e30f, l = 0.f;
        float o[NT];
        #pragma unroll
        for (int j = 0; j < NT; ++j) o[j] = 0.f;

        for (int i = 0; i < NG - 1; ++i) {   // rolled: keep I-cache small
            const float e0 = xr[4 + 2 * i];
            const float e1 = xr[5 + 2 * i];
            const float e2 = xr[34 + 2 * i];
            const float e3 = xr[35 + 2 * i];
            const float e4 = xr[64 + i];
            float h[NU];
            #pragma unroll
            for (int j = 0; j < NU; ++j) {
                float a = oa_b1[j];
                a += e0 * oa_w1[0 * NU + j];
                a += e1 * oa_w1[1 * NU + j];
                a += e2 * oa_w1[2 * NU + j];
                a += e3 * oa_w1[3 * NU + j];
                a += e4 * oa_w1[4 * NU + j];
                h[j] = fmaxf(a, 0.f);
            }
            float enc[NT];
            #pragma unroll
            for (int j = 0; j < NT; ++j) enc[j] = oa_b2[j];
            #pragma unroll
            for (int k = 0; k < NU; ++k) {
                const float hk = h[k];
                #pragma unroll
                for (int j = 0; j < NT; ++j) enc[j] += hk * oa_w2[k * NT + j];
            }
            float s = 0.f;
            #pragma unroll
            for (int j = 0; j < NT; ++j) {
                enc[j] = fmaxf(enc[j], 0.f);
                s += self_o[j] * enc[j];
            }
            s *= 0.25f;                       // / sqrt(16)
            const float mn = fmaxf(m, s);
            const float sc = __expf(m - mn);  // first iter: exp(-huge)=0
            const float p  = __expf(s - mn);
            l = l * sc + p;
            #pragma unroll
            for (int j = 0; j < NT; ++j) o[j] = o[j] * sc + p * enc[j];
            m = mn;
        }
        // normalize + LayerNorm + relu
        const float rl = 1.f / l;
        float mu = 0.f;
        #pragma unroll
        for (int j = 0; j < NT; ++j) { o[j] *= rl; mu += o[j]; }
        mu *= (1.f / NT);
        float var = 0.f;
        #pragma unroll
        for (int j = 0; j < NT; ++j) { const float d = o[j] - mu; var += d * d; }
        var *= (1.f / NT);
        const float inv = rsqrtf(var + 1e-5f);
        #pragma unroll
        for (int j = 0; j < NT; ++j)
            other_o[j] = fmaxf((o[j] - mu) * inv * oa_g[j] + oa_bln[j], 0.f);
    }

    // ---- food branch: 16 entities, 3 -> 32 -> 16, attend, LN+relu ----
    float food_o[NT];
    {
        float m = -1e30f, l = 0.f;
        float o[NT];
        #pragma unroll
        for (int j = 0; j < NT; ++j) o[j] = 0.f;

        for (int i = 0; i < NG; ++i) {
            const float e0 = xr[79 + 3 * i];
            const float e1 = xr[80 + 3 * i];
            const float e2 = xr[81 + 3 * i];
            float h[NU];
            #pragma unroll
            for (int j = 0; j < NU; ++j) {
                float a = g_b1[j];
                a += e0 * g_w1[0 * NU + j];
                a += e1 * g_w1[1 * NU + j];
                a += e2 * g_w1[2 * NU + j];
                h[j] = fmaxf(a, 0.f);
            }
            float enc[NT];
            #pragma unroll
            for (int j = 0; j < NT; ++j) enc[j] = g_b2[j];
            #pragma unroll
            for (int k = 0; k < NU; ++k) {
                const float hk = h[k];
                #pragma unroll
                for (int j = 0; j < NT; ++j) enc[j] += hk * g_w2[k * NT + j];
            }
            float s = 0.f;
            #pragma unroll
            for (int j = 0; j < NT; ++j) {
                enc[j] = fmaxf(enc[j], 0.f);
                s += self_o[j] * enc[j];
            }
            s *= 0.25f;
            const float mn = fmaxf(m, s);
            const float sc = __expf(m - mn);
            const float p  = __expf(s - mn);
            l = l * sc + p;
            #pragma unroll
            for (int j = 0; j < NT; ++j) o[j] = o[j] * sc + p * enc[j];
            m = mn;
        }
        const float rl = 1.f / l;
        float mu = 0.f;
        #pragma unroll
        for (int j = 0; j < NT; ++j) { o[j] *= rl; mu += o[j]; }
        mu *= (1.f / NT);
        float var = 0.f;
        #pragma unroll
        for (int j = 0; j < NT; ++j) { const float d = o[j] - mu; var += d * d; }
        var *= (1.f / NT);
        const float inv = rsqrtf(var + 1e-5f);
        #pragma unroll
        for (int j = 0; j < NT; ++j)
            food_o[j] = fmaxf((o[j] - mu) * inv * g_g[j] + g_bln[j], 0.f);
    }

    // ---- merge MLP: 48 -> 32 lrelu -> 32 lrelu -> 2 tanh ----
    // merged = [self_o, food_o, other_o]
    float h1[NU];
    #pragma unroll
    for (int j = 0; j < NU; ++j) {
        float a = m_b1[j];
        #pragma unroll
        for (int k = 0; k < NT; ++k) a += self_o[k]  * m_w1[(k)      * NU + j];
        #pragma unroll
        for (int k = 0; k < NT; ++k) a += food_o[k]  * m_w1[(16 + k) * NU + j];
        #pragma unroll
        for (int k = 0; k < NT; ++k) a += other_o[k] * m_w1[(32 + k) * NU + j];
        h1[j] = lrelu(a);
    }
    float h2[NU];
    #pragma unroll
    for (int j = 0; j < NU; ++j) {
        float a = m_b2[j];
        #pragma unroll
        for (int k = 0; k < NU; ++k) a += h1[k] * m_w2[k * NU + j];
        h2[j] = lrelu(a);
    }
    float o0 = m_b3[0], o1 = m_b3[1];
    #pragma unroll
    for (int k = 0; k < NU; ++k) {
        o0 += h2[k] * m_w3[2 * k];
        o1 += h2[k] * m_w3[2 * k + 1];
    }
    out[2 * (long)row]     = tanhf(o0);
    out[2 * (long)row + 1] = tanhf(o1);
}

extern "C" void kernel_launch(void* const* d_in, const int* in_sizes, int n_in,
                              void* d_out, int out_size, void* d_ws, size_t ws_size,
                              hipStream_t stream) {
    const int B = in_sizes[0] / OBS;
    const float* xin = (const float*)d_in[0];
    const float* en_w1 = (const float*)d_in[1];
    const float* en_b1 = (const float*)d_in[2];
    const float* en_w2 = (const float*)d_in[3];
    const float* en_b2 = (const float*)d_in[4];
    const float* oa_w1 = (const float*)d_in[5];
    const float* oa_b1 = (const float*)d_in[6];
    const float* oa_w2 = (const float*)d_in[7];
    const float* oa_b2 = (const float*)d_in[8];
    const float* oa_g  = (const float*)d_in[9];
    const float* oa_bl = (const float*)d_in[10];
    const float* g_w1  = (const float*)d_in[11];
    const float* g_b1  = (const float*)d_in[12];
    const float* g_w2  = (const float*)d_in[13];
    const float* g_b2  = (const float*)d_in[14];
    const float* g_g   = (const float*)d_in[15];
    const float* g_bl  = (const float*)d_in[16];
    const float* m_w1  = (const float*)d_in[17];
    const float* m_b1  = (const float*)d_in[18];
    const float* m_w2  = (const float*)d_in[19];
    const float* m_b2  = (const float*)d_in[20];
    const float* m_w3  = (const float*)d_in[21];
    const float* m_b3  = (const float*)d_in[22];

    const int block = 256;
    const int grid = (B + block - 1) / block;
    actor_kernel<<<grid, block, 0, stream>>>(
        xin, en_w1, en_b1, en_w2, en_b2,
        oa_w1, oa_b1, oa_w2, oa_b2, oa_g, oa_bl,
        g_w1, g_b1, g_w2, g_b2, g_g, g_bl,
        m_w1, m_b1, m_w2, m_b2, m_w3, m_b3,
        (float*)d_out, B);
}